// Round 1
// baseline (5468.932 us; speedup 1.0000x reference)
//
#include <hip/hip_runtime.h>
#include <math.h>

// NOVAE forward: encoder MLP -> cost matrix -> Sinkhorn(200) -> pi@z_prior -> decoder MLP.
// Round 1: correctness-first full-fp32. Sinkhorn = 400 matvec dispatches over
// L3-resident K / K^T (67 MB each). pi never materialized:
// z_sel = diag(u) * K * (diag(v) * z_prior).

namespace {

constexpr float REG = 0.05f;
constexpr int SINK_ITERS = 200;

enum { EPI_BIAS_RELU = 0, EPI_BIAS = 1, EPI_COST = 2, EPI_ROWSCALE = 3 };

// Tiled fp32 GEMM. A: MxK row-major. B: KxN row-major (BT=false) or NxK
// row-major used as B^T (BT=true). 64x64 tile, BK=16, 256 thr, 4x4/thread.
// Epilogues:
//   BIAS_RELU/BIAS: C = [relu](A@B + rb[col])
//   COST:           C = max(rb[row] + aux[col] - 2*A@B, 0), atomicMax -> maxOut
//   ROWSCALE:       C = rb[row] * (A@B)
template<int EPI, bool BT>
__global__ __launch_bounds__(256)
void gemm_f32(const float* __restrict__ A, const float* __restrict__ Bm,
              const float* __restrict__ rb, const float* __restrict__ aux,
              float* __restrict__ C, float* __restrict__ maxOut,
              int M, int N, int K)
{
    constexpr int BM = 64, BNt = 64, BK = 16;
    __shared__ float sA[BK][BM + 4];   // +4 pad: 16B-aligned float4, <=2-way banks
    __shared__ float sB[BK][BNt + 4];
    __shared__ float red[256];

    const int t  = threadIdx.x;
    const int tx = t & 15;
    const int ty = t >> 4;
    const int row0 = blockIdx.y * BM;
    const int col0 = blockIdx.x * BNt;

    // cooperative load mapping: 256 thr x float4 = 1024 elems = one 64x16 panel
    const int lr = t >> 2;            // 0..63 tile row
    const int lc = (t & 3) << 2;      // 0,4,8,12 k offset

    float acc[4][4] = {};

    for (int k0 = 0; k0 < K; k0 += BK) {
        {
            const float4 a4 = *(const float4*)&A[(size_t)(row0 + lr) * K + k0 + lc];
            sA[lc + 0][lr] = a4.x; sA[lc + 1][lr] = a4.y;
            sA[lc + 2][lr] = a4.z; sA[lc + 3][lr] = a4.w;
        }
        if constexpr (!BT) {
            const int br = t >> 4, bc = (t & 15) << 2;   // 16 k-rows x 64 cols
            const float4 b4 = *(const float4*)&Bm[(size_t)(k0 + br) * N + col0 + bc];
            *(float4*)&sB[br][bc] = b4;
        } else {
            const float4 b4 = *(const float4*)&Bm[(size_t)(col0 + lr) * K + k0 + lc];
            sB[lc + 0][lr] = b4.x; sB[lc + 1][lr] = b4.y;
            sB[lc + 2][lr] = b4.z; sB[lc + 3][lr] = b4.w;
        }
        __syncthreads();
        #pragma unroll
        for (int kk = 0; kk < BK; ++kk) {
            const float4 a4v = *(const float4*)&sA[kk][ty << 2];
            const float4 b4v = *(const float4*)&sB[kk][tx << 2];
            const float av[4] = {a4v.x, a4v.y, a4v.z, a4v.w};
            const float bv[4] = {b4v.x, b4v.y, b4v.z, b4v.w};
            #pragma unroll
            for (int i = 0; i < 4; ++i)
                #pragma unroll
                for (int j = 0; j < 4; ++j)
                    acc[i][j] = fmaf(av[i], bv[j], acc[i][j]);
        }
        __syncthreads();
    }

    if constexpr (EPI == EPI_COST) {
        float lmax = 0.0f;
        #pragma unroll
        for (int i = 0; i < 4; ++i) {
            const int r = row0 + (ty << 2) + i;
            const float znr = rb[r];
            #pragma unroll
            for (int j = 0; j < 4; ++j) {
                const int c = col0 + (tx << 2) + j;
                const float v = fmaxf(znr + aux[c] - 2.0f * acc[i][j], 0.0f);
                C[(size_t)r * N + c] = v;
                lmax = fmaxf(lmax, v);
            }
        }
        red[t] = lmax;
        __syncthreads();
        for (int s = 128; s > 0; s >>= 1) {
            if (t < s) red[t] = fmaxf(red[t], red[t + s]);
            __syncthreads();
        }
        // values >= 0 so int-bit compare == float compare
        if (t == 0) atomicMax((int*)maxOut, __float_as_int(red[0]));
    } else {
        #pragma unroll
        for (int i = 0; i < 4; ++i) {
            const int r = row0 + (ty << 2) + i;
            const float rs = (EPI == EPI_ROWSCALE) ? rb[r] : 0.0f;
            #pragma unroll
            for (int j = 0; j < 4; ++j) {
                const int c = col0 + (tx << 2) + j;
                float v = acc[i][j];
                if constexpr (EPI == EPI_BIAS || EPI == EPI_BIAS_RELU) v += rb[c];
                if constexpr (EPI == EPI_BIAS_RELU) v = fmaxf(v, 0.0f);
                if constexpr (EPI == EPI_ROWSCALE) v *= rs;
                C[(size_t)r * N + c] = v;
            }
        }
    }
}

// squared L2 norm of each 128-wide row; one wave per row (2 floats/lane)
__global__ __launch_bounds__(256)
void rownorm128_k(const float* __restrict__ X, float* __restrict__ out)
{
    const int row  = blockIdx.x * 4 + (threadIdx.x >> 6);
    const int lane = threadIdx.x & 63;
    const float2 v = ((const float2*)&X[(size_t)row * 128])[lane];
    float s = fmaf(v.x, v.x, v.y * v.y);
    #pragma unroll
    for (int o = 32; o > 0; o >>= 1) s += __shfl_down(s, o);
    if (lane == 0) out[row] = s;
}

__global__ void init_k(float* __restrict__ u, float* __restrict__ v,
                       float* __restrict__ mx)
{
    const int i = blockIdx.x * 256 + threadIdx.x;
    if (i < 4096) { u[i] = 1.0f / 4096.0f; v[i] = 1.0f / 4096.0f; }
    if (i == 0) *mx = 0.0f;
}

// K = exp(-M/(reg*(maxM+1e-12))) in place over M; also write K^T (LDS transpose)
__global__ __launch_bounds__(256)
void exp_transpose_k(float* __restrict__ MK, float* __restrict__ KT,
                     const float* __restrict__ mx)
{
    __shared__ float tile[32][33];
    const float s = -1.0f / (REG * (*mx + 1e-12f));
    const int tx  = threadIdx.x & 31;
    const int ty4 = threadIdx.x >> 5;              // 0..7
    const int i0 = blockIdx.y * 32, j0 = blockIdx.x * 32;
    #pragma unroll
    for (int r = 0; r < 4; ++r) {
        const int i = i0 + ty4 * 4 + r;
        const size_t idx = (size_t)i * 4096 + j0 + tx;
        const float k = expf(MK[idx] * s);
        MK[idx] = k;
        tile[ty4 * 4 + r][tx] = k;
    }
    __syncthreads();
    #pragma unroll
    for (int r = 0; r < 4; ++r)
        KT[(size_t)(j0 + ty4 * 4 + r) * 4096 + i0 + tx] = tile[tx][ty4 * 4 + r];
}

// y[row] = (1/4096) / dot(Mat[row,:], x) ; row length 4096; one wave per row
__global__ __launch_bounds__(256)
void matvec_recip_k(const float* __restrict__ Mat, const float* __restrict__ x,
                    float* __restrict__ y)
{
    const int row  = blockIdx.x * 4 + (threadIdx.x >> 6);
    const int lane = threadIdx.x & 63;
    const float4* m4 = (const float4*)&Mat[(size_t)row * 4096];
    const float4* x4 = (const float4*)x;
    float s = 0.0f;
    #pragma unroll
    for (int w = 0; w < 16; ++w) {
        const float4 m  = m4[lane + (w << 6)];
        const float4 xv = x4[lane + (w << 6)];
        s = fmaf(m.x, xv.x, s); s = fmaf(m.y, xv.y, s);
        s = fmaf(m.z, xv.z, s); s = fmaf(m.w, xv.w, s);
    }
    #pragma unroll
    for (int o = 32; o > 0; o >>= 1) s += __shfl_down(s, o);
    if (lane == 0) y[row] = (1.0f / 4096.0f) / s;
}

// W2[j][d] = v[j] * zp[j][d]
__global__ __launch_bounds__(256)
void vscale_k(const float* __restrict__ zp, const float* __restrict__ v,
              float* __restrict__ W2)
{
    const int idx = blockIdx.x * 256 + threadIdx.x;
    W2[idx] = zp[idx] * v[idx >> 7];
}

} // namespace

extern "C" void kernel_launch(void* const* d_in, const int* in_sizes, int n_in,
                              void* d_out, int out_size, void* d_ws, size_t ws_size,
                              hipStream_t stream)
{
    const float* x  = (const float*)d_in[0];
    const float* zp = (const float*)d_in[1];
    const float* ew[4] = {(const float*)d_in[2],  (const float*)d_in[4],
                          (const float*)d_in[6],  (const float*)d_in[8]};
    const float* eb[4] = {(const float*)d_in[3],  (const float*)d_in[5],
                          (const float*)d_in[7],  (const float*)d_in[9]};
    const float* dw[4] = {(const float*)d_in[10], (const float*)d_in[12],
                          (const float*)d_in[14], (const float*)d_in[16]};
    const float* db[4] = {(const float*)d_in[11], (const float*)d_in[13],
                          (const float*)d_in[15], (const float*)d_in[17]};
    float* out = (float*)d_out;

    char* w = (char*)d_ws;
    size_t off = 0;
    auto alloc = [&](size_t bytes) {
        float* p = (float*)(w + off);
        off += (bytes + 255) & ~size_t(255);
        return p;
    };
    float* Km   = alloc((size_t)4096 * 4096 * 4);  // M, then K in place
    float* KT   = alloc((size_t)4096 * 4096 * 4);
    float* a0   = alloc((size_t)4096 * 512 * 4);
    float* a1   = alloc((size_t)4096 * 1024 * 4);
    float* a2   = alloc((size_t)4096 * 512 * 4);
    float* z_   = alloc((size_t)4096 * 128 * 4);
    float* W2   = alloc((size_t)4096 * 128 * 4);
    float* zsel = alloc((size_t)4096 * 128 * 4);
    float* zn   = alloc(4096 * 4);
    float* pn   = alloc(4096 * 4);
    float* u    = alloc(4096 * 4);
    float* v    = alloc(4096 * 4);
    float* mx   = alloc(256);
    (void)ws_size; (void)in_sizes; (void)n_in; (void)out_size;

    const dim3 blk(256);

    // ---- encoder: 1024 -> 512 -> 1024 -> 512 -> 128
    gemm_f32<EPI_BIAS_RELU,false><<<dim3(512/64,  4096/64), blk, 0, stream>>>(x,  ew[0], eb[0], nullptr, a0, nullptr, 4096, 512, 1024);
    gemm_f32<EPI_BIAS_RELU,false><<<dim3(1024/64, 4096/64), blk, 0, stream>>>(a0, ew[1], eb[1], nullptr, a1, nullptr, 4096, 1024, 512);
    gemm_f32<EPI_BIAS_RELU,false><<<dim3(512/64,  4096/64), blk, 0, stream>>>(a1, ew[2], eb[2], nullptr, a2, nullptr, 4096, 512, 1024);
    gemm_f32<EPI_BIAS,     false><<<dim3(128/64,  4096/64), blk, 0, stream>>>(a2, ew[3], eb[3], nullptr, z_, nullptr, 4096, 128, 512);

    // ---- cost matrix + K/K^T
    rownorm128_k<<<1024, blk, 0, stream>>>(z_, zn);
    rownorm128_k<<<1024, blk, 0, stream>>>(zp, pn);
    init_k<<<16, blk, 0, stream>>>(u, v, mx);

    gemm_f32<EPI_COST,true><<<dim3(64, 64), blk, 0, stream>>>(z_, zp, zn, pn, Km, mx, 4096, 4096, 128);
    exp_transpose_k<<<dim3(128, 128), blk, 0, stream>>>(Km, KT, mx);

    // ---- Sinkhorn: v = b/(K^T u); u = a/(K v)
    for (int it = 0; it < SINK_ITERS; ++it) {
        matvec_recip_k<<<1024, blk, 0, stream>>>(KT, u, v);
        matvec_recip_k<<<1024, blk, 0, stream>>>(Km, v, u);
    }

    // ---- z_sel = diag(u) * K * (diag(v) * zp)
    vscale_k<<<2048, blk, 0, stream>>>(zp, v, W2);
    gemm_f32<EPI_ROWSCALE,false><<<dim3(128/64, 4096/64), blk, 0, stream>>>(Km, W2, u, nullptr, zsel, nullptr, 4096, 128, 4096);

    // ---- decoder: 128 -> 512 -> 1024 -> 512 -> 1024
    gemm_f32<EPI_BIAS_RELU,false><<<dim3(512/64,  4096/64), blk, 0, stream>>>(zsel, dw[0], db[0], nullptr, a0, nullptr, 4096, 512, 128);
    gemm_f32<EPI_BIAS_RELU,false><<<dim3(1024/64, 4096/64), blk, 0, stream>>>(a0,   dw[1], db[1], nullptr, a1, nullptr, 4096, 1024, 512);
    gemm_f32<EPI_BIAS_RELU,false><<<dim3(512/64,  4096/64), blk, 0, stream>>>(a1,   dw[2], db[2], nullptr, a2, nullptr, 4096, 512, 1024);
    gemm_f32<EPI_BIAS,     false><<<dim3(1024/64, 4096/64), blk, 0, stream>>>(a2,   dw[3], db[3], nullptr, out, nullptr, 4096, 1024, 512);
}

// Round 2
// 3480.274 us; speedup vs baseline: 1.5714x; 1.5714x over previous
//
#include <hip/hip_runtime.h>
#include <hip/hip_bf16.h>
#include <math.h>

// NOVAE forward: encoder MLP -> cost matrix -> Sinkhorn(200) -> pi@z_prior -> decoder MLP.
// Round 2: K / K^T stored bf16 for the Sinkhorn matvecs (fp32 accumulate).
// Halves the dominant byte stream (26.8 GB -> 13.4 GB, L3-resident).
// Coupling GEMM still reads fp32 K; MLP GEMMs unchanged fp32.

namespace {

constexpr float REG = 0.05f;
constexpr int SINK_ITERS = 200;

enum { EPI_BIAS_RELU = 0, EPI_BIAS = 1, EPI_COST = 2, EPI_ROWSCALE = 3 };

// Tiled fp32 GEMM. A: MxK row-major. B: KxN row-major (BT=false) or NxK
// row-major used as B^T (BT=true). 64x64 tile, BK=16, 256 thr, 4x4/thread.
template<int EPI, bool BT>
__global__ __launch_bounds__(256)
void gemm_f32(const float* __restrict__ A, const float* __restrict__ Bm,
              const float* __restrict__ rb, const float* __restrict__ aux,
              float* __restrict__ C, float* __restrict__ maxOut,
              int M, int N, int K)
{
    constexpr int BM = 64, BNt = 64, BK = 16;
    __shared__ float sA[BK][BM + 4];
    __shared__ float sB[BK][BNt + 4];
    __shared__ float red[256];

    const int t  = threadIdx.x;
    const int tx = t & 15;
    const int ty = t >> 4;
    const int row0 = blockIdx.y * BM;
    const int col0 = blockIdx.x * BNt;

    const int lr = t >> 2;            // 0..63 tile row
    const int lc = (t & 3) << 2;      // 0,4,8,12 k offset

    float acc[4][4] = {};

    for (int k0 = 0; k0 < K; k0 += BK) {
        {
            const float4 a4 = *(const float4*)&A[(size_t)(row0 + lr) * K + k0 + lc];
            sA[lc + 0][lr] = a4.x; sA[lc + 1][lr] = a4.y;
            sA[lc + 2][lr] = a4.z; sA[lc + 3][lr] = a4.w;
        }
        if constexpr (!BT) {
            const int br = t >> 4, bc = (t & 15) << 2;
            const float4 b4 = *(const float4*)&Bm[(size_t)(k0 + br) * N + col0 + bc];
            *(float4*)&sB[br][bc] = b4;
        } else {
            const float4 b4 = *(const float4*)&Bm[(size_t)(col0 + lr) * K + k0 + lc];
            sB[lc + 0][lr] = b4.x; sB[lc + 1][lr] = b4.y;
            sB[lc + 2][lr] = b4.z; sB[lc + 3][lr] = b4.w;
        }
        __syncthreads();
        #pragma unroll
        for (int kk = 0; kk < BK; ++kk) {
            const float4 a4v = *(const float4*)&sA[kk][ty << 2];
            const float4 b4v = *(const float4*)&sB[kk][tx << 2];
            const float av[4] = {a4v.x, a4v.y, a4v.z, a4v.w};
            const float bv[4] = {b4v.x, b4v.y, b4v.z, b4v.w};
            #pragma unroll
            for (int i = 0; i < 4; ++i)
                #pragma unroll
                for (int j = 0; j < 4; ++j)
                    acc[i][j] = fmaf(av[i], bv[j], acc[i][j]);
        }
        __syncthreads();
    }

    if constexpr (EPI == EPI_COST) {
        float lmax = 0.0f;
        #pragma unroll
        for (int i = 0; i < 4; ++i) {
            const int r = row0 + (ty << 2) + i;
            const float znr = rb[r];
            #pragma unroll
            for (int j = 0; j < 4; ++j) {
                const int c = col0 + (tx << 2) + j;
                const float v = fmaxf(znr + aux[c] - 2.0f * acc[i][j], 0.0f);
                C[(size_t)r * N + c] = v;
                lmax = fmaxf(lmax, v);
            }
        }
        red[t] = lmax;
        __syncthreads();
        for (int s = 128; s > 0; s >>= 1) {
            if (t < s) red[t] = fmaxf(red[t], red[t + s]);
            __syncthreads();
        }
        if (t == 0) atomicMax((int*)maxOut, __float_as_int(red[0]));
    } else {
        #pragma unroll
        for (int i = 0; i < 4; ++i) {
            const int r = row0 + (ty << 2) + i;
            const float rs = (EPI == EPI_ROWSCALE) ? rb[r] : 0.0f;
            #pragma unroll
            for (int j = 0; j < 4; ++j) {
                const int c = col0 + (tx << 2) + j;
                float v = acc[i][j];
                if constexpr (EPI == EPI_BIAS || EPI == EPI_BIAS_RELU) v += rb[c];
                if constexpr (EPI == EPI_BIAS_RELU) v = fmaxf(v, 0.0f);
                if constexpr (EPI == EPI_ROWSCALE) v *= rs;
                C[(size_t)r * N + c] = v;
            }
        }
    }
}

// squared L2 norm of each 128-wide row; one wave per row
__global__ __launch_bounds__(256)
void rownorm128_k(const float* __restrict__ X, float* __restrict__ out)
{
    const int row  = blockIdx.x * 4 + (threadIdx.x >> 6);
    const int lane = threadIdx.x & 63;
    const float2 v = ((const float2*)&X[(size_t)row * 128])[lane];
    float s = fmaf(v.x, v.x, v.y * v.y);
    #pragma unroll
    for (int o = 32; o > 0; o >>= 1) s += __shfl_down(s, o);
    if (lane == 0) out[row] = s;
}

__global__ void init_k(float* __restrict__ u, float* __restrict__ v,
                       float* __restrict__ mx)
{
    const int i = blockIdx.x * 256 + threadIdx.x;
    if (i < 4096) { u[i] = 1.0f / 4096.0f; v[i] = 1.0f / 4096.0f; }
    if (i == 0) *mx = 0.0f;
}

// K = exp(-M/(reg*(maxM+1e-12))): fp32 in place over M (for coupling GEMM),
// plus bf16 K and bf16 K^T (LDS transpose) for the Sinkhorn matvecs.
__global__ __launch_bounds__(256)
void exp_transpose_k(float* __restrict__ MK,
                     __hip_bfloat16* __restrict__ Kb,
                     __hip_bfloat16* __restrict__ KTb,
                     const float* __restrict__ mx)
{
    __shared__ float tile[32][33];
    const float s = -1.0f / (REG * (*mx + 1e-12f));
    const int tx  = threadIdx.x & 31;
    const int ty4 = threadIdx.x >> 5;              // 0..7
    const int i0 = blockIdx.y * 32, j0 = blockIdx.x * 32;
    #pragma unroll
    for (int r = 0; r < 4; ++r) {
        const int i = i0 + ty4 * 4 + r;
        const size_t idx = (size_t)i * 4096 + j0 + tx;
        const float k = expf(MK[idx] * s);
        MK[idx] = k;
        Kb[idx] = __float2bfloat16(k);
        tile[ty4 * 4 + r][tx] = k;
    }
    __syncthreads();
    #pragma unroll
    for (int r = 0; r < 4; ++r)
        KTb[(size_t)(j0 + ty4 * 4 + r) * 4096 + i0 + tx]
            = __float2bfloat16(tile[tx][ty4 * 4 + r]);
}

// y[row] = (1/4096) / dot(Mat[row,:], x); Mat bf16 4096-wide, fp32 accum.
// One wave per row, 16B (8 bf16) per lane per step.
__global__ __launch_bounds__(256)
void matvec_recip_bf16_k(const __hip_bfloat16* __restrict__ Mat,
                         const float* __restrict__ x,
                         float* __restrict__ y)
{
    const int row  = blockIdx.x * 4 + (threadIdx.x >> 6);
    const int lane = threadIdx.x & 63;
    const uint4*  m4 = (const uint4*)&Mat[(size_t)row * 4096];
    const float4* x4 = (const float4*)x;
    float s = 0.0f;
    #pragma unroll
    for (int w = 0; w < 8; ++w) {
        const int q = (w << 6) + lane;          // uint4 index: 8 bf16 each
        const uint4  m  = m4[q];
        const float4 xa = x4[q * 2];
        const float4 xb = x4[q * 2 + 1];
        // each uint32 = 2 bf16: low half-word is element 2k, high is 2k+1
        const float m0 = __uint_as_float(m.x << 16);
        const float m1 = __uint_as_float(m.x & 0xffff0000u);
        const float m2 = __uint_as_float(m.y << 16);
        const float m3 = __uint_as_float(m.y & 0xffff0000u);
        const float m4v = __uint_as_float(m.z << 16);
        const float m5 = __uint_as_float(m.z & 0xffff0000u);
        const float m6 = __uint_as_float(m.w << 16);
        const float m7 = __uint_as_float(m.w & 0xffff0000u);
        s = fmaf(m0, xa.x, s); s = fmaf(m1, xa.y, s);
        s = fmaf(m2, xa.z, s); s = fmaf(m3, xa.w, s);
        s = fmaf(m4v, xb.x, s); s = fmaf(m5, xb.y, s);
        s = fmaf(m6, xb.z, s); s = fmaf(m7, xb.w, s);
    }
    #pragma unroll
    for (int o = 32; o > 0; o >>= 1) s += __shfl_down(s, o);
    if (lane == 0) y[row] = (1.0f / 4096.0f) / s;
}

// W2[j][d] = v[j] * zp[j][d]
__global__ __launch_bounds__(256)
void vscale_k(const float* __restrict__ zp, const float* __restrict__ v,
              float* __restrict__ W2)
{
    const int idx = blockIdx.x * 256 + threadIdx.x;
    W2[idx] = zp[idx] * v[idx >> 7];
}

} // namespace

extern "C" void kernel_launch(void* const* d_in, const int* in_sizes, int n_in,
                              void* d_out, int out_size, void* d_ws, size_t ws_size,
                              hipStream_t stream)
{
    const float* x  = (const float*)d_in[0];
    const float* zp = (const float*)d_in[1];
    const float* ew[4] = {(const float*)d_in[2],  (const float*)d_in[4],
                          (const float*)d_in[6],  (const float*)d_in[8]};
    const float* eb[4] = {(const float*)d_in[3],  (const float*)d_in[5],
                          (const float*)d_in[7],  (const float*)d_in[9]};
    const float* dw[4] = {(const float*)d_in[10], (const float*)d_in[12],
                          (const float*)d_in[14], (const float*)d_in[16]};
    const float* db[4] = {(const float*)d_in[11], (const float*)d_in[13],
                          (const float*)d_in[15], (const float*)d_in[17]};
    float* out = (float*)d_out;

    char* w = (char*)d_ws;
    size_t off = 0;
    auto alloc = [&](size_t bytes) {
        void* p = (void*)(w + off);
        off += (bytes + 255) & ~size_t(255);
        return p;
    };
    float* Km = (float*)alloc((size_t)4096 * 4096 * 4);   // M, then fp32 K in place
    __hip_bfloat16* Kb  = (__hip_bfloat16*)alloc((size_t)4096 * 4096 * 2);
    __hip_bfloat16* KTb = (__hip_bfloat16*)alloc((size_t)4096 * 4096 * 2);
    float* a0   = (float*)alloc((size_t)4096 * 1024 * 4);
    float* a1   = (float*)alloc((size_t)4096 * 1024 * 4);
    float* a2   = (float*)alloc((size_t)4096 * 512 * 4);
    float* z_   = (float*)alloc((size_t)4096 * 128 * 4);
    float* W2   = (float*)alloc((size_t)4096 * 128 * 4);
    float* zsel = (float*)alloc((size_t)4096 * 128 * 4);
    float* zn   = (float*)alloc(4096 * 4);
    float* pn   = (float*)alloc(4096 * 4);
    float* u    = (float*)alloc(4096 * 4);
    float* v    = (float*)alloc(4096 * 4);
    float* mx   = (float*)alloc(256);
    (void)ws_size; (void)in_sizes; (void)n_in; (void)out_size;

    const dim3 blk(256);

    // ---- encoder: 1024 -> 512 -> 1024 -> 512 -> 128
    gemm_f32<EPI_BIAS_RELU,false><<<dim3(512/64,  4096/64), blk, 0, stream>>>(x,  ew[0], eb[0], nullptr, a0, nullptr, 4096, 512, 1024);
    gemm_f32<EPI_BIAS_RELU,false><<<dim3(1024/64, 4096/64), blk, 0, stream>>>(a0, ew[1], eb[1], nullptr, a1, nullptr, 4096, 1024, 512);
    gemm_f32<EPI_BIAS_RELU,false><<<dim3(512/64,  4096/64), blk, 0, stream>>>(a1, ew[2], eb[2], nullptr, a2, nullptr, 4096, 512, 1024);
    gemm_f32<EPI_BIAS,     false><<<dim3(128/64,  4096/64), blk, 0, stream>>>(a2, ew[3], eb[3], nullptr, z_, nullptr, 4096, 128, 512);

    // ---- cost matrix + K (fp32 + bf16 + bf16^T)
    rownorm128_k<<<1024, blk, 0, stream>>>(z_, zn);
    rownorm128_k<<<1024, blk, 0, stream>>>(zp, pn);
    init_k<<<16, blk, 0, stream>>>(u, v, mx);

    gemm_f32<EPI_COST,true><<<dim3(64, 64), blk, 0, stream>>>(z_, zp, zn, pn, Km, mx, 4096, 4096, 128);
    exp_transpose_k<<<dim3(128, 128), blk, 0, stream>>>(Km, Kb, KTb, mx);

    // ---- Sinkhorn: v = b/(K^T u); u = a/(K v)   (bf16 matrices, fp32 accum)
    for (int it = 0; it < SINK_ITERS; ++it) {
        matvec_recip_bf16_k<<<1024, blk, 0, stream>>>(KTb, u, v);
        matvec_recip_bf16_k<<<1024, blk, 0, stream>>>(Kb, v, u);
    }

    // ---- z_sel = diag(u) * K * (diag(v) * zp)   (fp32 K)
    vscale_k<<<2048, blk, 0, stream>>>(zp, v, W2);
    gemm_f32<EPI_ROWSCALE,false><<<dim3(128/64, 4096/64), blk, 0, stream>>>(Km, W2, u, nullptr, zsel, nullptr, 4096, 128, 4096);

    // ---- decoder: 128 -> 512 -> 1024 -> 512 -> 1024
    gemm_f32<EPI_BIAS_RELU,false><<<dim3(512/64,  4096/64), blk, 0, stream>>>(zsel, dw[0], db[0], nullptr, a0, nullptr, 4096, 512, 128);
    gemm_f32<EPI_BIAS_RELU,false><<<dim3(1024/64, 4096/64), blk, 0, stream>>>(a0,   dw[1], db[1], nullptr, a1, nullptr, 4096, 1024, 512);
    gemm_f32<EPI_BIAS_RELU,false><<<dim3(512/64,  4096/64), blk, 0, stream>>>(a1,   dw[2], db[2], nullptr, a2, nullptr, 4096, 512, 1024);
    gemm_f32<EPI_BIAS,     false><<<dim3(1024/64, 4096/64), blk, 0, stream>>>(a2,   dw[3], db[3], nullptr, out, nullptr, 4096, 1024, 512);
}

// Round 3
// 1596.825 us; speedup vs baseline: 3.4249x; 2.1795x over previous
//
#include <hip/hip_runtime.h>
#include <hip/hip_bf16.h>
#include <math.h>

// NOVAE forward: encoder MLP -> cost matrix -> Sinkhorn(200) -> pi@z_prior -> decoder MLP.
// Round 3: persistent-kernel Sinkhorn (one dispatch, custom two-level grid
// barrier, fixed row ownership) + convergence early-stop (rel-delta < 3e-6,
// checked every 8 iters, uniform across grid). Coupling GEMM reads bf16 K
// (consistent with the bf16 Sinkhorn fixed point); fp32 K never materialized.
// Grid = 256 blocks x 256 thr (1 block/CU, 8x occupancy headroom -> co-resident).

namespace {

constexpr float REG = 0.05f;
constexpr int SINK_ITERS = 200;
constexpr int NBLK = 256;                    // persistent grid: 1 block/CU
constexpr int ROWS_PER_WAVE = 4096 / NBLK / 4;  // 4 rows per wave
constexpr float STOP_EPS = 3e-6f;

enum { EPI_BIAS_RELU = 0, EPI_BIAS = 1, EPI_COST = 2, EPI_ROWSCALE = 3 };

// Tiled fp32 GEMM. A: MxK row-major (fp32, or bf16 if ABF16). B: KxN row-major
// (BT=false) or NxK row-major used as B^T (BT=true). 64x64 tile, BK=16.
template<int EPI, bool BT, bool ABF16 = false>
__global__ __launch_bounds__(256)
void gemm_f32(const float* __restrict__ A, const float* __restrict__ Bm,
              const float* __restrict__ rb, const float* __restrict__ aux,
              float* __restrict__ C, float* __restrict__ maxOut,
              int M, int N, int K)
{
    constexpr int BM = 64, BNt = 64, BK = 16;
    __shared__ float sA[BK][BM + 4];
    __shared__ float sB[BK][BNt + 4];
    __shared__ float red[256];

    const int t  = threadIdx.x;
    const int tx = t & 15;
    const int ty = t >> 4;
    const int row0 = blockIdx.y * BM;
    const int col0 = blockIdx.x * BNt;

    const int lr = t >> 2;            // 0..63 tile row
    const int lc = (t & 3) << 2;      // 0,4,8,12 k offset

    float acc[4][4] = {};

    for (int k0 = 0; k0 < K; k0 += BK) {
        if constexpr (!ABF16) {
            const float4 a4 = *(const float4*)&A[(size_t)(row0 + lr) * K + k0 + lc];
            sA[lc + 0][lr] = a4.x; sA[lc + 1][lr] = a4.y;
            sA[lc + 2][lr] = a4.z; sA[lc + 3][lr] = a4.w;
        } else {
            const unsigned short* Ab = (const unsigned short*)A;
            const uint2 a2 = *(const uint2*)&Ab[(size_t)(row0 + lr) * K + k0 + lc];
            sA[lc + 0][lr] = __uint_as_float(a2.x << 16);
            sA[lc + 1][lr] = __uint_as_float(a2.x & 0xffff0000u);
            sA[lc + 2][lr] = __uint_as_float(a2.y << 16);
            sA[lc + 3][lr] = __uint_as_float(a2.y & 0xffff0000u);
        }
        if constexpr (!BT) {
            const int br = t >> 4, bc = (t & 15) << 2;
            const float4 b4 = *(const float4*)&Bm[(size_t)(k0 + br) * N + col0 + bc];
            *(float4*)&sB[br][bc] = b4;
        } else {
            const float4 b4 = *(const float4*)&Bm[(size_t)(col0 + lr) * K + k0 + lc];
            sB[lc + 0][lr] = b4.x; sB[lc + 1][lr] = b4.y;
            sB[lc + 2][lr] = b4.z; sB[lc + 3][lr] = b4.w;
        }
        __syncthreads();
        #pragma unroll
        for (int kk = 0; kk < BK; ++kk) {
            const float4 a4v = *(const float4*)&sA[kk][ty << 2];
            const float4 b4v = *(const float4*)&sB[kk][tx << 2];
            const float av[4] = {a4v.x, a4v.y, a4v.z, a4v.w};
            const float bv[4] = {b4v.x, b4v.y, b4v.z, b4v.w};
            #pragma unroll
            for (int i = 0; i < 4; ++i)
                #pragma unroll
                for (int j = 0; j < 4; ++j)
                    acc[i][j] = fmaf(av[i], bv[j], acc[i][j]);
        }
        __syncthreads();
    }

    if constexpr (EPI == EPI_COST) {
        float lmax = 0.0f;
        #pragma unroll
        for (int i = 0; i < 4; ++i) {
            const int r = row0 + (ty << 2) + i;
            const float znr = rb[r];
            #pragma unroll
            for (int j = 0; j < 4; ++j) {
                const int c = col0 + (tx << 2) + j;
                const float v = fmaxf(znr + aux[c] - 2.0f * acc[i][j], 0.0f);
                C[(size_t)r * N + c] = v;
                lmax = fmaxf(lmax, v);
            }
        }
        red[t] = lmax;
        __syncthreads();
        for (int s = 128; s > 0; s >>= 1) {
            if (t < s) red[t] = fmaxf(red[t], red[t + s]);
            __syncthreads();
        }
        if (t == 0) atomicMax((int*)maxOut, __float_as_int(red[0]));
    } else {
        #pragma unroll
        for (int i = 0; i < 4; ++i) {
            const int r = row0 + (ty << 2) + i;
            const float rs = (EPI == EPI_ROWSCALE) ? rb[r] : 0.0f;
            #pragma unroll
            for (int j = 0; j < 4; ++j) {
                const int c = col0 + (tx << 2) + j;
                float v = acc[i][j];
                if constexpr (EPI == EPI_BIAS || EPI == EPI_BIAS_RELU) v += rb[c];
                if constexpr (EPI == EPI_BIAS_RELU) v = fmaxf(v, 0.0f);
                if constexpr (EPI == EPI_ROWSCALE) v *= rs;
                C[(size_t)r * N + c] = v;
            }
        }
    }
}

// squared L2 norm of each 128-wide row; one wave per row
__global__ __launch_bounds__(256)
void rownorm128_k(const float* __restrict__ X, float* __restrict__ out)
{
    const int row  = blockIdx.x * 4 + (threadIdx.x >> 6);
    const int lane = threadIdx.x & 63;
    const float2 v = ((const float2*)&X[(size_t)row * 128])[lane];
    float s = fmaf(v.x, v.x, v.y * v.y);
    #pragma unroll
    for (int o = 32; o > 0; o >>= 1) s += __shfl_down(s, o);
    if (lane == 0) out[row] = s;
}

// init u, v, max-scalar, early-stop slots, barrier state (ws is poisoned 0xAA
// before every call, so everything must be re-zeroed here)
__global__ void init_k(float* __restrict__ u, float* __restrict__ v,
                       float* __restrict__ mx, int* __restrict__ dmax,
                       int* __restrict__ bar)
{
    const int i = blockIdx.x * 256 + threadIdx.x;
    if (i < 4096) { u[i] = 1.0f / 4096.0f; v[i] = 1.0f / 4096.0f; }
    if (i == 0) *mx = 0.0f;
    if (blockIdx.x == 0) {
        if (threadIdx.x < 32) dmax[threadIdx.x] = 0;
        else if (threadIdx.x < 48) bar[threadIdx.x - 32] = 0;
    }
}

// K = exp(-M/(reg*(maxM+1e-12))): bf16 K and bf16 K^T (LDS transpose). M untouched.
__global__ __launch_bounds__(256)
void exp_transpose_k(const float* __restrict__ M,
                     unsigned short* __restrict__ Kb,
                     unsigned short* __restrict__ KTb,
                     const float* __restrict__ mx)
{
    __shared__ float tile[32][33];
    const float s = -1.0f / (REG * (*mx + 1e-12f));
    const int tx  = threadIdx.x & 31;
    const int ty4 = threadIdx.x >> 5;              // 0..7
    const int i0 = blockIdx.y * 32, j0 = blockIdx.x * 32;
    #pragma unroll
    for (int r = 0; r < 4; ++r) {
        const int i = i0 + ty4 * 4 + r;
        const size_t idx = (size_t)i * 4096 + j0 + tx;
        const float k = expf(M[idx] * s);
        Kb[idx] = (unsigned short)(__hip_bfloat16_raw(__float2bfloat16(k)).x);
        tile[ty4 * 4 + r][tx] = k;
    }
    __syncthreads();
    #pragma unroll
    for (int r = 0; r < 4; ++r) {
        const float k = tile[tx][ty4 * 4 + r];
        KTb[(size_t)(j0 + ty4 * 4 + r) * 4096 + i0 + tx]
            = (unsigned short)(__hip_bfloat16_raw(__float2bfloat16(k)).x);
    }
}

// two-level grid barrier: 8 groups of 32 blocks -> 1 global counter.
// Device-scope atomics + __threadfence() both sides (cross-XCD L2 visibility).
__device__ __forceinline__
void grid_barrier(int* lcnt, int* gcnt, int* ggen)
{
    __syncthreads();
    if (threadIdx.x == 0) {
        __threadfence();   // release my data writes (wbl2)
        const int gi = blockIdx.x & 7;
        const int g = __hip_atomic_load(ggen, __ATOMIC_RELAXED, __HIP_MEMORY_SCOPE_AGENT);
        if (__hip_atomic_fetch_add(&lcnt[gi], 1, __ATOMIC_ACQ_REL, __HIP_MEMORY_SCOPE_AGENT) == 31) {
            if (__hip_atomic_fetch_add(gcnt, 1, __ATOMIC_ACQ_REL, __HIP_MEMORY_SCOPE_AGENT) == 7) {
                #pragma unroll
                for (int i = 0; i < 8; ++i)
                    __hip_atomic_store(&lcnt[i], 0, __ATOMIC_RELAXED, __HIP_MEMORY_SCOPE_AGENT);
                __hip_atomic_store(gcnt, 0, __ATOMIC_RELAXED, __HIP_MEMORY_SCOPE_AGENT);
                __hip_atomic_store(ggen, g + 1, __ATOMIC_RELEASE, __HIP_MEMORY_SCOPE_AGENT);
            } else {
                while (__hip_atomic_load(ggen, __ATOMIC_ACQUIRE, __HIP_MEMORY_SCOPE_AGENT) == g)
                    __builtin_amdgcn_s_sleep(1);
            }
        } else {
            while (__hip_atomic_load(ggen, __ATOMIC_ACQUIRE, __HIP_MEMORY_SCOPE_AGENT) == g)
                __builtin_amdgcn_s_sleep(1);
        }
        __threadfence();   // acquire others' data writes (inv)
    }
    __syncthreads();
}

// one bf16 matvec row: s = dot(Mat[row,:], x), 4 accumulator chains
__device__ __forceinline__
float row_dot_bf16(const unsigned short* Mat, const float* x, int row, int lane)
{
    const uint4*  m4 = (const uint4*)(Mat + (size_t)row * 4096);
    const float4* x4 = (const float4*)x;
    float s0 = 0, s1 = 0, s2 = 0, s3 = 0;
    #pragma unroll
    for (int w = 0; w < 8; ++w) {
        const int q = (w << 6) + lane;
        const uint4  m  = m4[q];
        const float4 xa = x4[q * 2];
        const float4 xb = x4[q * 2 + 1];
        s0 = fmaf(__uint_as_float(m.x << 16),          xa.x, s0);
        s1 = fmaf(__uint_as_float(m.x & 0xffff0000u),  xa.y, s1);
        s2 = fmaf(__uint_as_float(m.y << 16),          xa.z, s2);
        s3 = fmaf(__uint_as_float(m.y & 0xffff0000u),  xa.w, s3);
        s0 = fmaf(__uint_as_float(m.z << 16),          xb.x, s0);
        s1 = fmaf(__uint_as_float(m.z & 0xffff0000u),  xb.y, s1);
        s2 = fmaf(__uint_as_float(m.w << 16),          xb.z, s2);
        s3 = fmaf(__uint_as_float(m.w & 0xffff0000u),  xb.w, s3);
    }
    float s = (s0 + s1) + (s2 + s3);
    #pragma unroll
    for (int o = 32; o > 0; o >>= 1) s += __shfl_down(s, o);
    return s;
}

// Persistent Sinkhorn: 200 iterations in one dispatch, early-stop on
// converged u (checked every 8 iters; uniform decision via pre-zeroed slots).
// Normal launch, 256 blocks x 256 thr = 1 block/CU (8x occupancy headroom).
__global__ __launch_bounds__(256, 1)
void sinkhorn_k(const unsigned short* __restrict__ Kb,
                const unsigned short* __restrict__ KTb,
                float* __restrict__ u, float* __restrict__ v,
                int* __restrict__ dmax, int* __restrict__ bar)
{
    int* lcnt = bar;
    int* gcnt = bar + 8;
    int* ggen = bar + 9;
    const int wv   = threadIdx.x >> 6;      // wave 0..3
    const int lane = threadIdx.x & 63;
    const int row0 = blockIdx.x * (ROWS_PER_WAVE * 4) + wv * ROWS_PER_WAVE;

    for (int it = 0; it < SINK_ITERS; ++it) {
        // ---- v = (1/N) / (K^T u)
        #pragma unroll
        for (int rr = 0; rr < ROWS_PER_WAVE; ++rr) {
            const int row = row0 + rr;
            const float s = row_dot_bf16(KTb, u, row, lane);
            if (lane == 0) v[row] = (1.0f / 4096.0f) / s;
        }
        grid_barrier(lcnt, gcnt, ggen);

        // ---- u = (1/N) / (K v), sample convergence every 8 iters
        const bool chk = ((it & 7) == 7);
        #pragma unroll
        for (int rr = 0; rr < ROWS_PER_WAVE; ++rr) {
            const int row = row0 + rr;
            const float s = row_dot_bf16(Kb, v, row, lane);
            if (lane == 0) {
                const float nu = (1.0f / 4096.0f) / s;
                if (chk) {
                    const float ou = u[row];
                    const float d = fabsf(nu - ou) / (fabsf(ou) + 1e-37f);
                    atomicMax(&dmax[it >> 3], __float_as_int(d));
                }
                u[row] = nu;
            }
        }
        grid_barrier(lcnt, gcnt, ggen);

        if (chk) {
            const float dm = __int_as_float(
                __hip_atomic_load(&dmax[it >> 3], __ATOMIC_RELAXED, __HIP_MEMORY_SCOPE_AGENT));
            if (dm < STOP_EPS) break;   // uniform across all blocks
        }
    }
}

// W2[j][d] = v[j] * zp[j][d]
__global__ __launch_bounds__(256)
void vscale_k(const float* __restrict__ zp, const float* __restrict__ v,
              float* __restrict__ W2)
{
    const int idx = blockIdx.x * 256 + threadIdx.x;
    W2[idx] = zp[idx] * v[idx >> 7];
}

} // namespace

extern "C" void kernel_launch(void* const* d_in, const int* in_sizes, int n_in,
                              void* d_out, int out_size, void* d_ws, size_t ws_size,
                              hipStream_t stream)
{
    const float* x  = (const float*)d_in[0];
    const float* zp = (const float*)d_in[1];
    const float* ew[4] = {(const float*)d_in[2],  (const float*)d_in[4],
                          (const float*)d_in[6],  (const float*)d_in[8]};
    const float* eb[4] = {(const float*)d_in[3],  (const float*)d_in[5],
                          (const float*)d_in[7],  (const float*)d_in[9]};
    const float* dw[4] = {(const float*)d_in[10], (const float*)d_in[12],
                          (const float*)d_in[14], (const float*)d_in[16]};
    const float* db[4] = {(const float*)d_in[11], (const float*)d_in[13],
                          (const float*)d_in[15], (const float*)d_in[17]};
    float* out = (float*)d_out;

    char* w = (char*)d_ws;
    size_t off = 0;
    auto alloc = [&](size_t bytes) {
        void* p = (void*)(w + off);
        off += (bytes + 255) & ~size_t(255);
        return p;
    };
    float* Mm = (float*)alloc((size_t)4096 * 4096 * 4);   // cost matrix M (fp32)
    unsigned short* Kb  = (unsigned short*)alloc((size_t)4096 * 4096 * 2);
    unsigned short* KTb = (unsigned short*)alloc((size_t)4096 * 4096 * 2);
    float* a0   = (float*)alloc((size_t)4096 * 1024 * 4);
    float* a1   = (float*)alloc((size_t)4096 * 1024 * 4);
    float* a2   = (float*)alloc((size_t)4096 * 512 * 4);
    float* z_   = (float*)alloc((size_t)4096 * 128 * 4);
    float* W2   = (float*)alloc((size_t)4096 * 128 * 4);
    float* zsel = (float*)alloc((size_t)4096 * 128 * 4);
    float* zn   = (float*)alloc(4096 * 4);
    float* pn   = (float*)alloc(4096 * 4);
    float* u    = (float*)alloc(4096 * 4);
    float* v    = (float*)alloc(4096 * 4);
    float* mx   = (float*)alloc(256);
    int*   dmax = (int*)alloc(32 * 4);
    int*   bar  = (int*)alloc(16 * 4);
    (void)ws_size; (void)in_sizes; (void)n_in; (void)out_size;

    const dim3 blk(256);

    // ---- encoder: 1024 -> 512 -> 1024 -> 512 -> 128
    gemm_f32<EPI_BIAS_RELU,false><<<dim3(512/64,  4096/64), blk, 0, stream>>>(x,  ew[0], eb[0], nullptr, a0, nullptr, 4096, 512, 1024);
    gemm_f32<EPI_BIAS_RELU,false><<<dim3(1024/64, 4096/64), blk, 0, stream>>>(a0, ew[1], eb[1], nullptr, a1, nullptr, 4096, 1024, 512);
    gemm_f32<EPI_BIAS_RELU,false><<<dim3(512/64,  4096/64), blk, 0, stream>>>(a1, ew[2], eb[2], nullptr, a2, nullptr, 4096, 512, 1024);
    gemm_f32<EPI_BIAS,     false><<<dim3(128/64,  4096/64), blk, 0, stream>>>(a2, ew[3], eb[3], nullptr, z_, nullptr, 4096, 128, 512);

    // ---- cost matrix + bf16 K / K^T
    rownorm128_k<<<1024, blk, 0, stream>>>(z_, zn);
    rownorm128_k<<<1024, blk, 0, stream>>>(zp, pn);
    init_k<<<16, blk, 0, stream>>>(u, v, mx, dmax, bar);

    gemm_f32<EPI_COST,true><<<dim3(64, 64), blk, 0, stream>>>(z_, zp, zn, pn, Mm, mx, 4096, 4096, 128);
    exp_transpose_k<<<dim3(128, 128), blk, 0, stream>>>(Mm, Kb, KTb, mx);

    // ---- Sinkhorn: one persistent dispatch
    sinkhorn_k<<<NBLK, blk, 0, stream>>>(Kb, KTb, u, v, dmax, bar);

    // ---- z_sel = diag(u) * K * (diag(v) * zp)   (bf16 K, fp32 accumulate)
    vscale_k<<<2048, blk, 0, stream>>>(zp, v, W2);
    gemm_f32<EPI_ROWSCALE,false,true><<<dim3(128/64, 4096/64), blk, 0, stream>>>((const float*)Kb, W2, u, nullptr, zsel, nullptr, 4096, 128, 4096);

    // ---- decoder: 128 -> 512 -> 1024 -> 512 -> 1024
    gemm_f32<EPI_BIAS_RELU,false><<<dim3(512/64,  4096/64), blk, 0, stream>>>(zsel, dw[0], db[0], nullptr, a0, nullptr, 4096, 512, 128);
    gemm_f32<EPI_BIAS_RELU,false><<<dim3(1024/64, 4096/64), blk, 0, stream>>>(a0,   dw[1], db[1], nullptr, a1, nullptr, 4096, 1024, 512);
    gemm_f32<EPI_BIAS_RELU,false><<<dim3(512/64,  4096/64), blk, 0, stream>>>(a1,   dw[2], db[2], nullptr, a2, nullptr, 4096, 512, 1024);
    gemm_f32<EPI_BIAS,     false><<<dim3(1024/64, 4096/64), blk, 0, stream>>>(a2,   dw[3], db[3], nullptr, out, nullptr, 4096, 1024, 512);
}